// Round 6
// baseline (838.957 us; speedup 1.0000x reference)
//
#include <hip/hip_runtime.h>
#include <cmath>

// ---------------------------------------------------------------------------
// DynamicProbSparseAttention: B=4, L=8192, D=1024, H=16, dk=64
//   5 launches:
//   1) k_convbias : x,w -> bf16 + out = broadcast(bo)
//   2) k_gemm_qkv : bf16 MFMA; Q never stored, sparsity score in epilogue
//                   (fast-math entropy identity: logS - sum(e*(q-m))/S)
//   3) k_candsel  : top-16 prefilter + fp64 exact rescore + top-10 + u-stats
//   4) k_attn_part: single-pass K/V sparse attention partials
//   5) k_mergescatter: merge partials, project through wo, atomic scatter
// ---------------------------------------------------------------------------

typedef short     s16x8 __attribute__((ext_vector_type(8)));
typedef unsigned short u16x8 __attribute__((ext_vector_type(8)));
typedef unsigned short u16x4 __attribute__((ext_vector_type(4)));
typedef float     f32x4 __attribute__((ext_vector_type(4)));

__device__ __forceinline__ unsigned short f2bf(float f) {
    unsigned u = __float_as_uint(f);
    u += 0x7fffu + ((u >> 16) & 1u);   // round-to-nearest-even
    return (unsigned short)(u >> 16);
}
__device__ __forceinline__ float bf2f(unsigned short s) {
    return __uint_as_float(((unsigned)s) << 16);
}

__device__ __forceinline__ void async16(const void* g, void* l) {
    __builtin_amdgcn_global_load_lds(
        (const __attribute__((address_space(1))) void*)g,
        (__attribute__((address_space(3))) void*)l, 16, 0, 0);
}

// ---------------- fused convert + output-bias kernel ----------------
__global__ void k_convbias(const float* __restrict__ x, const float* __restrict__ wq,
                           const float* __restrict__ wk, const float* __restrict__ wv,
                           const float* __restrict__ bo,
                           unsigned short* __restrict__ xb, unsigned short* __restrict__ wb,
                           float* __restrict__ out) {
    size_t i = (size_t)blockIdx.x * 256 + threadIdx.x;
    if (i < 8388608) {                       // x: 8388608 float4s
        float4 v = ((const float4*)x)[i];
        ushort4 o; o.x = f2bf(v.x); o.y = f2bf(v.y); o.z = f2bf(v.z); o.w = f2bf(v.w);
        ((ushort4*)xb)[i] = o;
    } else if (i < 9175040) {                // weights: 786432 float4s
        size_t j = i - 8388608;
        size_t wsel = j >> 18, rem = j & 262143;
        const float* src = wsel == 0 ? wq : (wsel == 1 ? wk : wv);
        float4 v = ((const float4*)src)[rem];
        ushort4 o; o.x = f2bf(v.x); o.y = f2bf(v.y); o.z = f2bf(v.z); o.w = f2bf(v.w);
        ((ushort4*)wb)[j] = o;
    } else {                                 // out bias: 8388608 float4s
        size_t j = i - 9175040;
        ((float4*)out)[j] = ((const float4*)bo)[j & 255];
    }
}

// ---------------- fused QKV GEMM (C = x @ W^T + b), bf16 MFMA ----------------
// natural block order (24 consecutive blocks share one mt x-tile; XCD swizzle
// measured WORSE in R4: FETCH 287->530 MB). wsel==0: score epilogue, no Q store.
__global__ __launch_bounds__(256) void k_gemm_qkv(
    const unsigned short* __restrict__ xb, const unsigned short* __restrict__ wb,
    const float* __restrict__ bq, const float* __restrict__ bk, const float* __restrict__ bv,
    unsigned short* __restrict__ Kb, unsigned short* __restrict__ Vb,
    float* __restrict__ scores)
{
    __shared__ unsigned short As[128 * 32];
    __shared__ unsigned short Bs[128 * 32];
    int bid = blockIdx.x;
    int mt = bid / 24, rem = bid % 24;
    int wsel = rem >> 3, nt = rem & 7;
    const unsigned short* wbase = wb + ((size_t)wsel << 20) + ((size_t)nt * 128) * 1024;
    const float* bias = wsel == 0 ? bq : (wsel == 1 ? bk : bv);
    unsigned short* outp = wsel == 1 ? Kb : Vb;
    int tid = threadIdx.x, wave = tid >> 6, lane = tid & 63;
    int ml = lane & 15, quad = lane >> 4, wm = wave >> 1, wn = wave & 1;
    int lr = lane >> 2, lc = lane & 3;
    const unsigned short* xbase = xb + ((size_t)mt * 128) * 1024;

    f32x4 acc[4][4] = {};
    for (int k0 = 0; k0 < 1024; k0 += 32) {
#pragma unroll
        for (int s = 0; s < 2; ++s) {
            int seg = wave * 2 + s;
            int row = seg * 16 + lr;
            async16(xbase + (size_t)row * 1024 + k0 + lc * 8, &As[seg * 512]);
            async16(wbase + (size_t)row * 1024 + k0 + lc * 8, &Bs[seg * 512]);
        }
        __builtin_amdgcn_s_waitcnt(0);
        __syncthreads();
        s16x8 a[4], b[4];
#pragma unroll
        for (int i = 0; i < 4; ++i) a[i] = *(const s16x8*)&As[(wm * 64 + i * 16 + ml) * 32 + quad * 8];
#pragma unroll
        for (int j = 0; j < 4; ++j) b[j] = *(const s16x8*)&Bs[(wn * 64 + j * 16 + ml) * 32 + quad * 8];
#pragma unroll
        for (int i = 0; i < 4; ++i)
#pragma unroll
            for (int j = 0; j < 4; ++j)
                acc[i][j] = __builtin_amdgcn_mfma_f32_16x16x32_bf16(a[i], b[j], acc[i][j], 0, 0, 0);
        __syncthreads();
    }

    float bvv[4];
#pragma unroll
    for (int j = 0; j < 4; ++j) bvv[j] = bias[nt * 128 + wn * 64 + j * 16 + ml];

    if (wsel == 0) {
        // score epilogue: quad's 16 lanes hold a full 64-wide Q row of head hh.
        // entropy via identity: -sum p log p = logS - sum(e*(q-m))/S (no eps;
        // exact fp64 rescore downstream decides the final selection).
        int hh = nt * 2 + wn;
#pragma unroll
        for (int i = 0; i < 4; ++i) {
#pragma unroll
            for (int r = 0; r < 4; ++r) {
                float q0 = acc[i][0][r] + bvv[0];
                float q1 = acc[i][1][r] + bvv[1];
                float q2 = acc[i][2][r] + bvv[2];
                float q3 = acc[i][3][r] + bvv[3];
                float mx = fmaxf(fmaxf(q0, q1), fmaxf(q2, q3));
                float sm = q0 + q1 + q2 + q3;
                float ss = q0 * q0 + q1 * q1 + q2 * q2 + q3 * q3;
#pragma unroll
                for (int off = 1; off < 16; off <<= 1) {
                    mx = fmaxf(mx, __shfl_xor(mx, off));
                    sm += __shfl_xor(sm, off);
                    ss += __shfl_xor(ss, off);
                }
                float e0 = __expf(q0 - mx), e1 = __expf(q1 - mx);
                float e2 = __expf(q2 - mx), e3 = __expf(q3 - mx);
                float S  = e0 + e1 + e2 + e3;
                float wsum = e0 * (q0 - mx) + e1 * (q1 - mx) + e2 * (q2 - mx) + e3 * (q3 - mx);
#pragma unroll
                for (int off = 1; off < 16; off <<= 1) {
                    S    += __shfl_xor(S, off);
                    wsum += __shfl_xor(wsum, off);
                }
                float ent = __logf(S) - wsum / S;
                float mean = sm * (1.f / 64.f);
                float d0 = q0 - mean, d1 = q1 - mean, d2 = q2 - mean, d3 = q3 - mean;
                float var = d0 * d0 + d1 * d1 + d2 * d2 + d3 * d3;
#pragma unroll
                for (int off = 1; off < 16; off <<= 1) var += __shfl_xor(var, off);
                if (ml == 0) {
                    float sc = 0.5f * sqrtf(ss) + 0.3f * ent + 0.2f * (var * (1.f / 63.f));
                    int row = mt * 128 + wm * 64 + i * 16 + quad * 4 + r;
                    scores[(size_t)(((row >> 13) << 4) + hh) * 8192 + (row & 8191)] = sc;
                }
            }
        }
    } else {
#pragma unroll
        for (int i = 0; i < 4; ++i) {
            int grow0 = mt * 128 + wm * 64 + i * 16 + quad * 4;
#pragma unroll
            for (int j = 0; j < 4; ++j) {
                int gcol = nt * 128 + wn * 64 + j * 16 + ml;
#pragma unroll
                for (int r = 0; r < 4; ++r)
                    outp[(size_t)(grow0 + r) * 1024 + gcol] = f2bf(acc[i][j][r] + bvv[j]);
            }
        }
    }
}

// ---------------- fused: top-16 + u-stats + fp64 rescore + top-10 ----------------
__global__ __launch_bounds__(1024) void k_candsel(
    const float* __restrict__ scores, const float* __restrict__ x,
    const float* __restrict__ wq, const float* __restrict__ bq,
    int* __restrict__ u, int* __restrict__ sel, float* __restrict__ selq)
{
    int pair = blockIdx.x; int b = pair >> 4, h = pair & 15;
    int t = threadIdx.x;
    __shared__ float  s_lds[8192];
    __shared__ double dred[1024];
    __shared__ float  wvv[16];
    __shared__ int    wii[16];
    __shared__ int    cand_s[16];
    __shared__ double dq[16][64];
    __shared__ double csc[16];
    __shared__ int    order[10];

    const float* sp = scores + (size_t)pair * 8192;
    for (int i = t; i < 8192; i += 1024) s_lds[i] = sp[i];
    __syncthreads();

    if ((pair & 15) == 0) {     // head 0: u[b] from these scores
        double a0 = 0;
#pragma unroll
        for (int k = 0; k < 8; ++k) a0 += (double)s_lds[t + k * 1024];
        dred[t] = a0; __syncthreads();
        for (int st = 512; st > 0; st >>= 1) { if (t < st) dred[t] += dred[t + st]; __syncthreads(); }
        double mean = dred[0] / 8192.0;
        __syncthreads();
        double a1 = 0;
#pragma unroll
        for (int k = 0; k < 8; ++k) { double d = (double)s_lds[t + k * 1024] - mean; a1 += d * d; }
        dred[t] = a1; __syncthreads();
        for (int st = 512; st > 0; st >>= 1) { if (t < st) dred[t] += dred[t + st]; __syncthreads(); }
        if (t == 0) {
            double sd = sqrt(dred[0] / 8191.0);
            double ratio = sd / (mean + 1e-6) * 10.0;
            int f = (int)rint(ratio);
            f = f < 3 ? 3 : (f > 10 ? 10 : f);
            u[pair >> 4] = f;
        }
        __syncthreads();
    }

    // 16x iterative argmax (tie -> lower index, matches top_k stability)
    for (int it = 0; it < 16; ++it) {
        float bv = -1e30f; int bi = 0x7fffffff;
#pragma unroll
        for (int k = 0; k < 8; ++k) {
            int i = t + k * 1024;
            float v = s_lds[i];
            if (v > bv || (v == bv && i < bi)) { bv = v; bi = i; }
        }
#pragma unroll
        for (int off = 32; off > 0; off >>= 1) {
            float ov = __shfl_down(bv, off);
            int   oi = __shfl_down(bi, off);
            if (ov > bv || (ov == bv && oi < bi)) { bv = ov; bi = oi; }
        }
        if ((t & 63) == 0) { wvv[t >> 6] = bv; wii[t >> 6] = bi; }
        __syncthreads();
        if (t == 0) {
            float fv = wvv[0]; int fi = wii[0];
            for (int k = 1; k < 16; ++k)
                if (wvv[k] > fv || (wvv[k] == fv && wii[k] < fi)) { fv = wvv[k]; fi = wii[k]; }
            cand_s[it] = fi;
            s_lds[fi] = -1e30f;
        }
        __syncthreads();
    }

    // exact fp64 rescore: wave c handles candidate c; lane d computes qrow[d]
    int c = t >> 6, d = t & 63;
    int l = cand_s[c];
    const float* xr = x + ((size_t)b * 8192 + l) * 1024;
    const float* wr = wq + (size_t)(h * 64 + d) * 1024;
    double p0 = 0, p1 = 0, p2 = 0, p3 = 0;
    for (int k = 0; k < 1024; k += 4) {
        float4 w4 = *(const float4*)(wr + k);
        float4 x4 = *(const float4*)(xr + k);
        p0 += (double)w4.x * x4.x; p1 += (double)w4.y * x4.y;
        p2 += (double)w4.z * x4.z; p3 += (double)w4.w * x4.w;
    }
    double q = p0 + p1 + p2 + p3 + (double)bq[h * 64 + d];
    dq[c][d] = q;
    // per-wave fp64 stats (reference formula incl. +1e-9 eps)
    double m = q;
#pragma unroll
    for (int off = 32; off > 0; off >>= 1) m = fmax(m, __shfl_down(m, off));
    m = __shfl(m, 0);
    double e = exp(q - m);
    double sum = q, sumsq = q * q, S = e;
#pragma unroll
    for (int off = 32; off > 0; off >>= 1) {
        sum += __shfl_down(sum, off);
        sumsq += __shfl_down(sumsq, off);
        S += __shfl_down(S, off);
    }
    sum = __shfl(sum, 0); sumsq = __shfl(sumsq, 0); S = __shfl(S, 0);
    double pp = e / S;
    double entc = -pp * log(pp + 1e-9);
    double mean = sum / 64.0;
    double dv = q - mean;
    double varc = dv * dv;
#pragma unroll
    for (int off = 32; off > 0; off >>= 1) {
        entc += __shfl_down(entc, off);
        varc += __shfl_down(varc, off);
    }
    if (d == 0) csc[c] = 0.5 * sqrt(sumsq) + 0.3 * entc + 0.2 * (varc / 63.0);
    __syncthreads();

    if (t == 0) {
        bool used[16] = {};
        for (int r = 0; r < 10; ++r) {
            int best = -1;
            for (int cc = 0; cc < 16; ++cc) {
                if (used[cc]) continue;
                if (best < 0 || csc[cc] > csc[best] ||
                    (csc[cc] == csc[best] && cand_s[cc] < cand_s[best])) best = cc;
            }
            used[best] = true; order[r] = best;
            sel[pair * 10 + r] = cand_s[best];
        }
    }
    __syncthreads();
    if (t < 640)
        selq[(size_t)pair * 640 + t] = (float)dq[order[t >> 6]][t & 63];
}

// ---------------- attention partials: one K/V pass, 256-row chunks ----------------
__global__ __launch_bounds__(256) void k_attn_part(
    const unsigned short* __restrict__ Kb, const unsigned short* __restrict__ Vb,
    const float* __restrict__ selq, const int* __restrict__ u,
    float* __restrict__ part)
{
    int bid = blockIdx.x;
    int pair = bid >> 5, chunk = bid & 31;
    int b = pair >> 4, h = pair & 15;
    int uu = u[b];
    int t = threadIdx.x, wave = t >> 6, lane = t & 63;

    __shared__ float q_sh[10][64];
    __shared__ float w_sh[10][256];
    __shared__ unsigned short V_sh[256][68];
    __shared__ float mc_sh[10][2], Sc_sh[10][2];

    size_t kvbase = ((size_t)b * 8192 + (size_t)chunk * 256) * 1024 + h * 64;

    for (int i = t; i < uu * 64; i += 256)
        q_sh[i >> 6][i & 63] = selq[(size_t)pair * 640 + i] * 0.125f;

    const u16x8* kr = (const u16x8*)(Kb + kvbase + (size_t)t * 1024);
    const u16x8* vr = (const u16x8*)(Vb + kvbase + (size_t)t * 1024);
    u16x8 vreg[8];
#pragma unroll
    for (int k8 = 0; k8 < 8; ++k8) vreg[k8] = vr[k8];
#pragma unroll
    for (int k8 = 0; k8 < 8; ++k8) {
        *(u16x4*)&V_sh[t][k8 * 8]     = { vreg[k8][0], vreg[k8][1], vreg[k8][2], vreg[k8][3] };
        *(u16x4*)&V_sh[t][k8 * 8 + 4] = { vreg[k8][4], vreg[k8][5], vreg[k8][6], vreg[k8][7] };
    }
    float krow[64];
#pragma unroll
    for (int k8 = 0; k8 < 8; ++k8) {
        u16x8 kv = kr[k8];
#pragma unroll
        for (int e = 0; e < 8; ++e) krow[k8 * 8 + e] = bf2f(kv[e]);
    }
    __syncthreads();

    for (int rr = 0; rr < uu; ++rr) {
        const float4* qp = (const float4*)q_sh[rr];
        float acc = 0.f;
#pragma unroll
        for (int i4 = 0; i4 < 16; ++i4) {
            float4 q4 = qp[i4];
            acc += q4.x * krow[i4 * 4] + q4.y * krow[i4 * 4 + 1] +
                   q4.z * krow[i4 * 4 + 2] + q4.w * krow[i4 * 4 + 3];
        }
        w_sh[rr][t] = acc;
    }
    __syncthreads();

    for (int rr = wave; rr < uu; rr += 4) {
        float4 wv = *(const float4*)&w_sh[rr][lane * 4];
        float m4 = fmaxf(fmaxf(wv.x, wv.y), fmaxf(wv.z, wv.w));
#pragma unroll
        for (int off = 16; off > 0; off >>= 1) m4 = fmaxf(m4, __shfl_xor(m4, off));
        float e0 = __expf(wv.x - m4), e1 = __expf(wv.y - m4);
        float e2 = __expf(wv.z - m4), e3 = __expf(wv.w - m4);
        float s = e0 + e1 + e2 + e3;
#pragma unroll
        for (int off = 16; off > 0; off >>= 1) s += __shfl_xor(s, off);
        float4 ev = { e0, e1, e2, e3 };
        *(float4*)&w_sh[rr][lane * 4] = ev;
        if ((lane & 31) == 0) { int jh = lane >> 5; mc_sh[rr][jh] = m4; Sc_sh[rr][jh] = s; }
    }
    __syncthreads();

    int jh = t >> 7, tt = t & 127, dp = tt & 31;
    for (int rr = tt >> 5; rr < uu; rr += 4) {
        float o0 = 0.f, o1 = 0.f;
        int j0 = jh * 128;
        for (int j = j0; j < j0 + 128; j += 4) {
            float4 w4 = *(const float4*)&w_sh[rr][j];
#pragma unroll
            for (int jj = 0; jj < 4; ++jj) {
                unsigned v = *(const unsigned*)&V_sh[j + jj][dp * 2];
                float w1 = jj == 0 ? w4.x : (jj == 1 ? w4.y : (jj == 2 ? w4.z : w4.w));
                o0 += w1 * __uint_as_float(v << 16);
                o1 += w1 * __uint_as_float(v & 0xffff0000u);
            }
        }
        float* pp = part + (((size_t)pair * 10 + rr) * 64 + chunk * 2 + jh) * 66;
        float2 o2 = { o0, o1 };
        *(float2*)&pp[2 + dp * 2] = o2;
        if (dp == 0) { pp[0] = mc_sh[rr][jh]; pp[1] = Sc_sh[rr][jh]; }
    }
}

// ---------------- fused merge + sparse scatter ----------------
__global__ __launch_bounds__(256) void k_mergescatter(
    const float* __restrict__ part, const int* __restrict__ sel,
    const int* __restrict__ u, const float* __restrict__ wo,
    float* __restrict__ out)
{
    int idx = blockIdx.x; int pair = idx / 10; int r = idx % 10;
    int b = pair >> 4, h = pair & 15;
    if (r >= u[b]) return;
    int t = threadIdx.x;
    __shared__ float a_sh[64];
    if (t < 64) {
        const float* base = part + ((size_t)pair * 10 + r) * 64 * 66;
        float m = -1e30f;
        for (int c = 0; c < 64; ++c) m = fmaxf(m, base[c * 66]);
        float S = 0, o = 0;
        for (int c = 0; c < 64; ++c) {
            float f = __expf(base[c * 66] - m);
            S += f * base[c * 66 + 1];
            o += f * base[c * 66 + 2 + t];
        }
        a_sh[t] = o / S;
    }
    __syncthreads();
    int l = sel[pair * 10 + r];
    float* orow = out + ((size_t)b * 8192 + l) * 1024;
    for (int j = t; j < 1024; j += 256) {
        const float* wr = wo + (size_t)j * 1024 + h * 64;
        float acc = 0;
#pragma unroll
        for (int d = 0; d < 64; d += 4) {
            float4 w4 = *(const float4*)(wr + d);
            acc += a_sh[d] * w4.x + a_sh[d + 1] * w4.y + a_sh[d + 2] * w4.z + a_sh[d + 3] * w4.w;
        }
        atomicAdd(orow + j, acc);
    }
}

// ---------------- workspace layout ----------------
static constexpr size_t OFF_XB    = 0;                        // 67108864
static constexpr size_t OFF_WB    = OFF_XB + 67108864;        // 6291456
static constexpr size_t OFF_KB    = OFF_WB + 6291456;         // 67108864
static constexpr size_t OFF_VB    = OFF_KB + 67108864;        // 67108864
static constexpr size_t OFF_SC    = OFF_VB + 67108864;        // 2097152
static constexpr size_t OFF_U     = OFF_SC + 2097152;         // 256
static constexpr size_t OFF_SEL   = OFF_U + 256;              // 4096
static constexpr size_t OFF_SELQ  = OFF_SEL + 4096;           // 163840
static constexpr size_t OFF_PART  = OFF_SELQ + 163840;        // 10813440
static constexpr size_t WS_NEED   = OFF_PART + 10813440;

extern "C" void kernel_launch(void* const* d_in, const int* in_sizes, int n_in,
                              void* d_out, int out_size, void* d_ws, size_t ws_size,
                              hipStream_t stream)
{
    const float* x  = (const float*)d_in[0];
    const float* wq = (const float*)d_in[1];
    const float* bq = (const float*)d_in[2];
    const float* wk = (const float*)d_in[3];
    const float* bk = (const float*)d_in[4];
    const float* wv = (const float*)d_in[5];
    const float* bv = (const float*)d_in[6];
    const float* wo = (const float*)d_in[7];
    const float* bo = (const float*)d_in[8];
    float* out = (float*)d_out;

    if (ws_size < WS_NEED) return;

    char* ws = (char*)d_ws;
    unsigned short* xb = (unsigned short*)(ws + OFF_XB);
    unsigned short* wb = (unsigned short*)(ws + OFF_WB);
    unsigned short* Kb = (unsigned short*)(ws + OFF_KB);
    unsigned short* Vb = (unsigned short*)(ws + OFF_VB);
    float*  scores = (float*)(ws + OFF_SC);
    int*    u      = (int*)(ws + OFF_U);
    int*    sel    = (int*)(ws + OFF_SEL);
    float*  selq   = (float*)(ws + OFF_SELQ);
    float*  part   = (float*)(ws + OFF_PART);

    k_convbias    <<<68608, 256,  0, stream>>>(x, wq, wk, wv, bo, xb, wb, out);
    k_gemm_qkv    <<<6144,  256,  0, stream>>>(xb, wb, bq, bk, bv, Kb, Vb, scores);
    k_candsel     <<<64,    1024, 0, stream>>>(scores, x, wq, bq, u, sel, selq);
    k_attn_part   <<<2048,  256,  0, stream>>>(Kb, Vb, selq, u, part);
    k_mergescatter<<<640,   256,  0, stream>>>(part, sel, u, wo, out);
}

// Round 7
// 737.645 us; speedup vs baseline: 1.1373x; 1.1373x over previous
//
#include <hip/hip_runtime.h>
#include <cmath>

// ---------------------------------------------------------------------------
// DynamicProbSparseAttention: B=4, L=8192, D=1024, H=16, dk=64
//   8 launches:
//   1) k_convbias : x,w -> bf16 + out = broadcast(bo)
//   2) k_gemm_qkv : bf16 MFMA, plain store epilogue for Q,K,V (R3-proven;
//      in-epilogue scoring measured +45us of MFMA-pipe stall in R5/R6)
//   3) k_score    : 8 threads per (row,head), coalesced, __expf, ~20us
//   4) k_cand     : top-16 prefilter + u-stats (64 blocks x 1024)
//   5) k_rescore  : exact fp64 rescore, 1024 blocks (R5-proven; 64-block
//      fused variant measured +105us in R6)
//   6) k_select   : top-10-of-16
//   7) k_attn_part: single-pass K/V sparse attention partials
//   8) k_mergescatter: merge partials, project through wo, atomic scatter
// ---------------------------------------------------------------------------

typedef short     s16x8 __attribute__((ext_vector_type(8)));
typedef unsigned short u16x8 __attribute__((ext_vector_type(8)));
typedef unsigned short u16x4 __attribute__((ext_vector_type(4)));
typedef float     f32x4 __attribute__((ext_vector_type(4)));

__device__ __forceinline__ unsigned short f2bf(float f) {
    unsigned u = __float_as_uint(f);
    u += 0x7fffu + ((u >> 16) & 1u);   // round-to-nearest-even
    return (unsigned short)(u >> 16);
}
__device__ __forceinline__ float bf2f(unsigned short s) {
    return __uint_as_float(((unsigned)s) << 16);
}

__device__ __forceinline__ void async16(const void* g, void* l) {
    __builtin_amdgcn_global_load_lds(
        (const __attribute__((address_space(1))) void*)g,
        (__attribute__((address_space(3))) void*)l, 16, 0, 0);
}

// ---------------- fused convert + output-bias kernel ----------------
__global__ void k_convbias(const float* __restrict__ x, const float* __restrict__ wq,
                           const float* __restrict__ wk, const float* __restrict__ wv,
                           const float* __restrict__ bo,
                           unsigned short* __restrict__ xb, unsigned short* __restrict__ wb,
                           float* __restrict__ out) {
    size_t i = (size_t)blockIdx.x * 256 + threadIdx.x;
    if (i < 8388608) {                       // x: 8388608 float4s
        float4 v = ((const float4*)x)[i];
        ushort4 o; o.x = f2bf(v.x); o.y = f2bf(v.y); o.z = f2bf(v.z); o.w = f2bf(v.w);
        ((ushort4*)xb)[i] = o;
    } else if (i < 9175040) {                // weights: 786432 float4s
        size_t j = i - 8388608;
        size_t wsel = j >> 18, rem = j & 262143;
        const float* src = wsel == 0 ? wq : (wsel == 1 ? wk : wv);
        float4 v = ((const float4*)src)[rem];
        ushort4 o; o.x = f2bf(v.x); o.y = f2bf(v.y); o.z = f2bf(v.z); o.w = f2bf(v.w);
        ((ushort4*)wb)[j] = o;
    } else {                                 // out bias: 8388608 float4s
        size_t j = i - 9175040;
        ((float4*)out)[j] = ((const float4*)bo)[j & 255];
    }
}

// ---------------- fused QKV GEMM (C = x @ W^T + b), bf16 MFMA ----------------
// natural block order (24 consecutive blocks share one mt x-tile; XCD swizzle
// measured WORSE in R4). Plain store epilogue (R3-proven 270us).
__global__ __launch_bounds__(256) void k_gemm_qkv(
    const unsigned short* __restrict__ xb, const unsigned short* __restrict__ wb,
    const float* __restrict__ bq, const float* __restrict__ bk, const float* __restrict__ bv,
    unsigned short* __restrict__ Qb, unsigned short* __restrict__ Kb, unsigned short* __restrict__ Vb)
{
    __shared__ unsigned short As[128 * 32];
    __shared__ unsigned short Bs[128 * 32];
    int bid = blockIdx.x;
    int mt = bid / 24, rem = bid % 24;
    int wsel = rem >> 3, nt = rem & 7;
    const unsigned short* wbase = wb + ((size_t)wsel << 20) + ((size_t)nt * 128) * 1024;
    const float* bias = wsel == 0 ? bq : (wsel == 1 ? bk : bv);
    unsigned short* outp = wsel == 0 ? Qb : (wsel == 1 ? Kb : Vb);
    int tid = threadIdx.x, wave = tid >> 6, lane = tid & 63;
    int ml = lane & 15, quad = lane >> 4, wm = wave >> 1, wn = wave & 1;
    int lr = lane >> 2, lc = lane & 3;
    const unsigned short* xbase = xb + ((size_t)mt * 128) * 1024;

    f32x4 acc[4][4] = {};
    for (int k0 = 0; k0 < 1024; k0 += 32) {
#pragma unroll
        for (int s = 0; s < 2; ++s) {
            int seg = wave * 2 + s;
            int row = seg * 16 + lr;
            async16(xbase + (size_t)row * 1024 + k0 + lc * 8, &As[seg * 512]);
            async16(wbase + (size_t)row * 1024 + k0 + lc * 8, &Bs[seg * 512]);
        }
        __builtin_amdgcn_s_waitcnt(0);
        __syncthreads();
        s16x8 a[4], b[4];
#pragma unroll
        for (int i = 0; i < 4; ++i) a[i] = *(const s16x8*)&As[(wm * 64 + i * 16 + ml) * 32 + quad * 8];
#pragma unroll
        for (int j = 0; j < 4; ++j) b[j] = *(const s16x8*)&Bs[(wn * 64 + j * 16 + ml) * 32 + quad * 8];
#pragma unroll
        for (int i = 0; i < 4; ++i)
#pragma unroll
            for (int j = 0; j < 4; ++j)
                acc[i][j] = __builtin_amdgcn_mfma_f32_16x16x32_bf16(a[i], b[j], acc[i][j], 0, 0, 0);
        __syncthreads();
    }
#pragma unroll
    for (int i = 0; i < 4; ++i) {
        int grow0 = mt * 128 + wm * 64 + i * 16 + quad * 4;
#pragma unroll
        for (int j = 0; j < 4; ++j) {
            int gcol = nt * 128 + wn * 64 + j * 16 + ml;
            float bvv = bias[gcol];
#pragma unroll
            for (int r = 0; r < 4; ++r)
                outp[(size_t)(grow0 + r) * 1024 + gcol] = f2bf(acc[i][j][r] + bvv);
        }
    }
}

// ---------------- sparsity scores: 8 threads per (row,head) ----------------
// coalesced 16B/lane Q reads; 8-lane xor-shuffle reductions; __expf +
// entropy identity (-sum p log p = logS - sum(e*(q-m))/S).
__global__ void k_score(const unsigned short* __restrict__ Qb, float* __restrict__ scores) {
    int gid = blockIdx.x * 256 + threadIdx.x;   // 4194304 threads
    int item = gid >> 3, sub = gid & 7;
    int r = item >> 4, h = item & 15;
    u16x8 v = ((const u16x8*)(Qb + (size_t)r * 1024 + h * 64))[sub];
    float q[8];
#pragma unroll
    for (int e = 0; e < 8; ++e) q[e] = bf2f(v[e]);

    float mx = q[0];
#pragma unroll
    for (int e = 1; e < 8; ++e) mx = fmaxf(mx, q[e]);
#pragma unroll
    for (int off = 1; off < 8; off <<= 1) mx = fmaxf(mx, __shfl_xor(mx, off));

    float sm = 0.f, ss = 0.f, S = 0.f, wsum = 0.f;
#pragma unroll
    for (int e = 0; e < 8; ++e) {
        float qe = q[e];
        sm += qe; ss += qe * qe;
        float ex = __expf(qe - mx);
        S += ex; wsum += ex * (qe - mx);
    }
#pragma unroll
    for (int off = 1; off < 8; off <<= 1) {
        sm += __shfl_xor(sm, off);
        ss += __shfl_xor(ss, off);
        S  += __shfl_xor(S, off);
        wsum += __shfl_xor(wsum, off);
    }
    float mean = sm * (1.f / 64.f);
    float vs = 0.f;
#pragma unroll
    for (int e = 0; e < 8; ++e) { float d = q[e] - mean; vs += d * d; }
#pragma unroll
    for (int off = 1; off < 8; off <<= 1) vs += __shfl_xor(vs, off);

    if (sub == 0) {
        float ent = __logf(S) - wsum / S;
        float sc = 0.5f * sqrtf(ss) + 0.3f * ent + 0.2f * (vs * (1.f / 63.f));
        scores[(size_t)(((r >> 13) << 4) + h) * 8192 + (r & 8191)] = sc;
    }
}

// ---------------- top-16 candidates + (h==0) u-stats, per pair ----------------
__global__ __launch_bounds__(1024) void k_cand(const float* __restrict__ scores,
                                               int* __restrict__ cand, int* __restrict__ u)
{
    int pair = blockIdx.x; int t = threadIdx.x;
    __shared__ float  s_lds[8192];
    __shared__ double dred[1024];
    __shared__ float  wvv[16];
    __shared__ int    wii[16];
    const float* sp = scores + (size_t)pair * 8192;
    for (int i = t; i < 8192; i += 1024) s_lds[i] = sp[i];
    __syncthreads();

    if ((pair & 15) == 0) {     // head 0: u[b] from these scores
        double a0 = 0;
#pragma unroll
        for (int k = 0; k < 8; ++k) a0 += (double)s_lds[t + k * 1024];
        dred[t] = a0; __syncthreads();
        for (int st = 512; st > 0; st >>= 1) { if (t < st) dred[t] += dred[t + st]; __syncthreads(); }
        double mean = dred[0] / 8192.0;
        __syncthreads();
        double a1 = 0;
#pragma unroll
        for (int k = 0; k < 8; ++k) { double d = (double)s_lds[t + k * 1024] - mean; a1 += d * d; }
        dred[t] = a1; __syncthreads();
        for (int st = 512; st > 0; st >>= 1) { if (t < st) dred[t] += dred[t + st]; __syncthreads(); }
        if (t == 0) {
            double sd = sqrt(dred[0] / 8191.0);
            double ratio = sd / (mean + 1e-6) * 10.0;
            int f = (int)rint(ratio);
            f = f < 3 ? 3 : (f > 10 ? 10 : f);
            u[pair >> 4] = f;
        }
        __syncthreads();
    }

    for (int it = 0; it < 16; ++it) {
        float bv = -1e30f; int bi = 0x7fffffff;
#pragma unroll
        for (int k = 0; k < 8; ++k) {
            int i = t + k * 1024;
            float v = s_lds[i];
            if (v > bv || (v == bv && i < bi)) { bv = v; bi = i; }
        }
#pragma unroll
        for (int off = 32; off > 0; off >>= 1) {
            float ov = __shfl_down(bv, off);
            int   oi = __shfl_down(bi, off);
            if (ov > bv || (ov == bv && oi < bi)) { bv = ov; bi = oi; }
        }
        if ((t & 63) == 0) { wvv[t >> 6] = bv; wii[t >> 6] = bi; }
        __syncthreads();
        if (t == 0) {
            float fv = wvv[0]; int fi = wii[0];
            for (int k = 1; k < 16; ++k)
                if (wvv[k] > fv || (wvv[k] == fv && wii[k] < fi)) { fv = wvv[k]; fi = wii[k]; }
            cand[pair * 16 + it] = fi;
            s_lds[fi] = -1e30f;
        }
        __syncthreads();
    }
}

// ---------------- exact fp64 rescore, one block per (pair,candidate) ----------------
__global__ __launch_bounds__(256) void k_rescore(
    const int* __restrict__ cand, const float* __restrict__ x,
    const float* __restrict__ wq, const float* __restrict__ bq,
    double* __restrict__ cscore, float* __restrict__ cq)
{
    int bid = blockIdx.x;             // pair*16 + c
    int pair = bid >> 4;
    int b = pair >> 4, h = pair & 15;
    int t = threadIdx.x;
    __shared__ float  xrow[1024];
    __shared__ double dred[256];
    __shared__ double qrow[64];

    int l = cand[bid];
    const float* xr = x + ((size_t)b * 8192 + l) * 1024;
    for (int i = t; i < 1024; i += 256) xrow[i] = xr[i];
    __syncthreads();

    int d = t >> 2, ks = t & 3;
    const float* wr = wq + (size_t)(h * 64 + d) * 1024 + ks * 256;
    const float* xs = xrow + ks * 256;
    double p = 0;
    for (int k = 0; k < 256; k += 4) {
        float4 w4 = *(const float4*)(wr + k);
        float4 x4 = *(const float4*)(xs + k);
        p += (double)w4.x * x4.x + (double)w4.y * x4.y +
             (double)w4.z * x4.z + (double)w4.w * x4.w;
    }
    dred[t] = p; __syncthreads();
    if ((t & 3) == 0)
        qrow[t >> 2] = dred[t] + dred[t + 1] + dred[t + 2] + dred[t + 3] + (double)bq[h * 64 + (t >> 2)];
    __syncthreads();

    if (t < 64) {
        double q = qrow[t];
        cq[(size_t)bid * 64 + t] = (float)q;
        double m = q;
#pragma unroll
        for (int off = 32; off > 0; off >>= 1) m = fmax(m, __shfl_down(m, off));
        m = __shfl(m, 0);
        double e = exp(q - m);
        double sum = q, sumsq = q * q, S = e;
#pragma unroll
        for (int off = 32; off > 0; off >>= 1) {
            sum += __shfl_down(sum, off);
            sumsq += __shfl_down(sumsq, off);
            S += __shfl_down(S, off);
        }
        sum = __shfl(sum, 0); sumsq = __shfl(sumsq, 0); S = __shfl(S, 0);
        double pp = e / S;
        double entc = -pp * log(pp + 1e-9);
        double mean = sum / 64.0;
        double dv = q - mean;
        double varc = dv * dv;
#pragma unroll
        for (int off = 32; off > 0; off >>= 1) {
            entc += __shfl_down(entc, off);
            varc += __shfl_down(varc, off);
        }
        if (t == 0)
            cscore[bid] = 0.5 * sqrt(sumsq) + 0.3 * entc + 0.2 * (varc / 63.0);
    }
}

// ---------------- top-10-of-16 select ----------------
__global__ void k_select(const int* __restrict__ cand, const double* __restrict__ cscore,
                         const float* __restrict__ cq,
                         int* __restrict__ sel, float* __restrict__ selq)
{
    int pair = blockIdx.x; int t = threadIdx.x;   // 64 threads
    __shared__ int order[10];
    if (t == 0) {
        bool used[16] = {};
        for (int r = 0; r < 10; ++r) {
            int best = -1;
            for (int c = 0; c < 16; ++c) {
                if (used[c]) continue;
                int ic = pair * 16 + c;
                if (best < 0 || cscore[ic] > cscore[pair * 16 + best] ||
                    (cscore[ic] == cscore[pair * 16 + best] && cand[ic] < cand[pair * 16 + best]))
                    best = c;
            }
            used[best] = true; order[r] = best;
            sel[pair * 10 + r] = cand[pair * 16 + best];
        }
    }
    __syncthreads();
    for (int r = 0; r < 10; ++r)
        selq[((size_t)pair * 10 + r) * 64 + t] = cq[((size_t)pair * 16 + order[r]) * 64 + t];
}

// ---------------- attention partials: one K/V pass, 256-row chunks ----------------
__global__ __launch_bounds__(256) void k_attn_part(
    const unsigned short* __restrict__ Kb, const unsigned short* __restrict__ Vb,
    const float* __restrict__ selq, const int* __restrict__ u,
    float* __restrict__ part)
{
    int bid = blockIdx.x;
    int pair = bid >> 5, chunk = bid & 31;
    int b = pair >> 4, h = pair & 15;
    int uu = u[b];
    int t = threadIdx.x, wave = t >> 6, lane = t & 63;

    __shared__ float q_sh[10][64];
    __shared__ float w_sh[10][256];
    __shared__ unsigned short V_sh[256][68];
    __shared__ float mc_sh[10][2], Sc_sh[10][2];

    size_t kvbase = ((size_t)b * 8192 + (size_t)chunk * 256) * 1024 + h * 64;

    for (int i = t; i < uu * 64; i += 256)
        q_sh[i >> 6][i & 63] = selq[(size_t)pair * 640 + i] * 0.125f;

    const u16x8* kr = (const u16x8*)(Kb + kvbase + (size_t)t * 1024);
    const u16x8* vr = (const u16x8*)(Vb + kvbase + (size_t)t * 1024);
    u16x8 vreg[8];
#pragma unroll
    for (int k8 = 0; k8 < 8; ++k8) vreg[k8] = vr[k8];
#pragma unroll
    for (int k8 = 0; k8 < 8; ++k8) {
        *(u16x4*)&V_sh[t][k8 * 8]     = { vreg[k8][0], vreg[k8][1], vreg[k8][2], vreg[k8][3] };
        *(u16x4*)&V_sh[t][k8 * 8 + 4] = { vreg[k8][4], vreg[k8][5], vreg[k8][6], vreg[k8][7] };
    }
    float krow[64];
#pragma unroll
    for (int k8 = 0; k8 < 8; ++k8) {
        u16x8 kv = kr[k8];
#pragma unroll
        for (int e = 0; e < 8; ++e) krow[k8 * 8 + e] = bf2f(kv[e]);
    }
    __syncthreads();

    for (int rr = 0; rr < uu; ++rr) {
        const float4* qp = (const float4*)q_sh[rr];
        float acc = 0.f;
#pragma unroll
        for (int i4 = 0; i4 < 16; ++i4) {
            float4 q4 = qp[i4];
            acc += q4.x * krow[i4 * 4] + q4.y * krow[i4 * 4 + 1] +
                   q4.z * krow[i4 * 4 + 2] + q4.w * krow[i4 * 4 + 3];
        }
        w_sh[rr][t] = acc;
    }
    __syncthreads();

    for (int rr = wave; rr < uu; rr += 4) {
        float4 wv = *(const float4*)&w_sh[rr][lane * 4];
        float m4 = fmaxf(fmaxf(wv.x, wv.y), fmaxf(wv.z, wv.w));
#pragma unroll
        for (int off = 16; off > 0; off >>= 1) m4 = fmaxf(m4, __shfl_xor(m4, off));
        float e0 = __expf(wv.x - m4), e1 = __expf(wv.y - m4);
        float e2 = __expf(wv.z - m4), e3 = __expf(wv.w - m4);
        float s = e0 + e1 + e2 + e3;
#pragma unroll
        for (int off = 16; off > 0; off >>= 1) s += __shfl_xor(s, off);
        float4 ev = { e0, e1, e2, e3 };
        *(float4*)&w_sh[rr][lane * 4] = ev;
        if ((lane & 31) == 0) { int jh = lane >> 5; mc_sh[rr][jh] = m4; Sc_sh[rr][jh] = s; }
    }
    __syncthreads();

    int jh = t >> 7, tt = t & 127, dp = tt & 31;
    for (int rr = tt >> 5; rr < uu; rr += 4) {
        float o0 = 0.f, o1 = 0.f;
        int j0 = jh * 128;
        for (int j = j0; j < j0 + 128; j += 4) {
            float4 w4 = *(const float4*)&w_sh[rr][j];
#pragma unroll
            for (int jj = 0; jj < 4; ++jj) {
                unsigned v = *(const unsigned*)&V_sh[j + jj][dp * 2];
                float w1 = jj == 0 ? w4.x : (jj == 1 ? w4.y : (jj == 2 ? w4.z : w4.w));
                o0 += w1 * __uint_as_float(v << 16);
                o1 += w1 * __uint_as_float(v & 0xffff0000u);
            }
        }
        float* pp = part + (((size_t)pair * 10 + rr) * 64 + chunk * 2 + jh) * 66;
        float2 o2 = { o0, o1 };
        *(float2*)&pp[2 + dp * 2] = o2;
        if (dp == 0) { pp[0] = mc_sh[rr][jh]; pp[1] = Sc_sh[rr][jh]; }
    }
}

// ---------------- fused merge + sparse scatter ----------------
__global__ __launch_bounds__(256) void k_mergescatter(
    const float* __restrict__ part, const int* __restrict__ sel,
    const int* __restrict__ u, const float* __restrict__ wo,
    float* __restrict__ out)
{
    int idx = blockIdx.x; int pair = idx / 10; int r = idx % 10;
    int b = pair >> 4, h = pair & 15;
    if (r >= u[b]) return;
    int t = threadIdx.x;
    __shared__ float a_sh[64];
    if (t < 64) {
        const float* base = part + ((size_t)pair * 10 + r) * 64 * 66;
        float m = -1e30f;
        for (int c = 0; c < 64; ++c) m = fmaxf(m, base[c * 66]);
        float S = 0, o = 0;
        for (int c = 0; c < 64; ++c) {
            float f = __expf(base[c * 66] - m);
            S += f * base[c * 66 + 1];
            o += f * base[c * 66 + 2 + t];
        }
        a_sh[t] = o / S;
    }
    __syncthreads();
    int l = sel[pair * 10 + r];
    float* orow = out + ((size_t)b * 8192 + l) * 1024;
    for (int j = t; j < 1024; j += 256) {
        const float* wr = wo + (size_t)j * 1024 + h * 64;
        float acc = 0;
#pragma unroll
        for (int d = 0; d < 64; d += 4) {
            float4 w4 = *(const float4*)(wr + d);
            acc += a_sh[d] * w4.x + a_sh[d + 1] * w4.y + a_sh[d + 2] * w4.z + a_sh[d + 3] * w4.w;
        }
        atomicAdd(orow + j, acc);
    }
}

// ---------------- workspace layout ----------------
static constexpr size_t OFF_XB    = 0;                        // 67108864
static constexpr size_t OFF_WB    = OFF_XB + 67108864;        // 6291456
static constexpr size_t OFF_QB    = OFF_WB + 6291456;         // 67108864
static constexpr size_t OFF_KB    = OFF_QB + 67108864;        // 67108864
static constexpr size_t OFF_VB    = OFF_KB + 67108864;        // 67108864
static constexpr size_t OFF_SC    = OFF_VB + 67108864;        // 2097152
static constexpr size_t OFF_U     = OFF_SC + 2097152;         // 256
static constexpr size_t OFF_SEL   = OFF_U + 256;              // 4096
static constexpr size_t OFF_SELQ  = OFF_SEL + 4096;           // 163840
static constexpr size_t OFF_PART  = OFF_SELQ + 163840;        // 10813440
static constexpr size_t OFF_CAND  = OFF_PART + 10813440;      // 4096
static constexpr size_t OFF_CSC   = OFF_CAND + 4096;          // 8192
static constexpr size_t OFF_CQ    = OFF_CSC + 8192;           // 262144
static constexpr size_t WS_NEED   = OFF_CQ + 262144;

extern "C" void kernel_launch(void* const* d_in, const int* in_sizes, int n_in,
                              void* d_out, int out_size, void* d_ws, size_t ws_size,
                              hipStream_t stream)
{
    const float* x  = (const float*)d_in[0];
    const float* wq = (const float*)d_in[1];
    const float* bq = (const float*)d_in[2];
    const float* wk = (const float*)d_in[3];
    const float* bk = (const float*)d_in[4];
    const float* wv = (const float*)d_in[5];
    const float* bv = (const float*)d_in[6];
    const float* wo = (const float*)d_in[7];
    const float* bo = (const float*)d_in[8];
    float* out = (float*)d_out;

    if (ws_size < WS_NEED) return;

    char* ws = (char*)d_ws;
    unsigned short* xb = (unsigned short*)(ws + OFF_XB);
    unsigned short* wb = (unsigned short*)(ws + OFF_WB);
    unsigned short* Qb = (unsigned short*)(ws + OFF_QB);
    unsigned short* Kb = (unsigned short*)(ws + OFF_KB);
    unsigned short* Vb = (unsigned short*)(ws + OFF_VB);
    float*  scores = (float*)(ws + OFF_SC);
    int*    u      = (int*)(ws + OFF_U);
    int*    sel    = (int*)(ws + OFF_SEL);
    float*  selq   = (float*)(ws + OFF_SELQ);
    float*  part   = (float*)(ws + OFF_PART);
    int*    cand   = (int*)(ws + OFF_CAND);
    double* cscore = (double*)(ws + OFF_CSC);
    float*  cq     = (float*)(ws + OFF_CQ);

    k_convbias    <<<68608, 256,  0, stream>>>(x, wq, wk, wv, bo, xb, wb, out);
    k_gemm_qkv    <<<6144,  256,  0, stream>>>(xb, wb, bq, bk, bv, Qb, Kb, Vb);
    k_score       <<<16384, 256,  0, stream>>>(Qb, scores);
    k_cand        <<<64,    1024, 0, stream>>>(scores, cand, u);
    k_rescore     <<<1024,  256,  0, stream>>>(cand, x, wq, bq, cscore, cq);
    k_select      <<<64,    64,   0, stream>>>(cand, cscore, cq, sel, selq);
    k_attn_part   <<<2048,  256,  0, stream>>>(Kb, Vb, selq, u, part);
    k_mergescatter<<<640,   256,  0, stream>>>(part, sel, u, wo, out);
}